// Round 7
// baseline (122.877 us; speedup 1.0000x reference)
//
#include <hip/hip_runtime.h>

// GCN 2-layer forward — gather formulation, SLICE-MAJOR bf16 gather table
// (3 tables of [N][32] bf16, each 3.2MB -> L2-resident per XCD), atomic-free
// parallel CSR build. Requires N <= 65536. Here N=50000, E=800000.
//
// h' = bf16( (x @ W) * dinv[row] )   stored slice-major
// out[i] = act( dinv[i] * ( sum_{e: dst=i} h'[src_e] + h'[i] ) + b )

#define NBINS_CAP 256   // bin = dst>>8  (N <= 65536)
#define MAXBLK 512      // max binA chunks (E <= 512*2048)
#define CHUNK 2048      // edges per binA block

__device__ __forceinline__ unsigned short f2bf(float f) {
    unsigned u = __float_as_uint(f);
    u = u + 0x7FFFu + ((u >> 16) & 1u);  // round-to-nearest-even
    return (unsigned short)(u >> 16);
}
__device__ __forceinline__ float bflo(unsigned w) { return __uint_as_float(w << 16); }
__device__ __forceinline__ float bfhi(unsigned w) { return __uint_as_float(w & 0xFFFF0000u); }

// ---------- binA: per-chunk LDS counting sort; coalesced slab write ----------
template <int NT>
__global__ __launch_bounds__(NT) void binA_kernel(const int* __restrict__ src,
                                                  const int* __restrict__ dst,
                                                  unsigned* __restrict__ slab,
                                                  int* __restrict__ cnt,
                                                  int* __restrict__ seg,
                                                  int nbins, int E) {
    constexpr int PT = CHUNK / NT;
    __shared__ unsigned ebuf[CHUNK];
    __shared__ int hist[NBINS_CAP];
    __shared__ int cur[NBINS_CAP];
    __shared__ int sc[NT];
    const int tid = threadIdx.x;
    const int beg = blockIdx.x * CHUNK;
    const int cntE = min(CHUNK, E - beg);
    for (int i = tid; i < nbins; i += NT) hist[i] = 0;
    __syncthreads();
    unsigned pv[PT];
    int pb[PT];
#pragma unroll
    for (int j = 0; j < PT; ++j) {
        int idx = j * NT + tid;
        if (idx < cntE) {
            int e = beg + idx;
            int s = src[e], d = dst[e];
            pb[j] = d >> 8;
            pv[j] = ((unsigned)(d & 255) << 16) | (unsigned)s;
            atomicAdd(&hist[pb[j]], 1);
        } else {
            pb[j] = -1;
        }
    }
    __syncthreads();
    int v = (tid < nbins) ? hist[tid] : 0;
    sc[tid] = v;
    __syncthreads();
    for (int off = 1; off < NT; off <<= 1) {
        int t = (tid >= off) ? sc[tid - off] : 0;
        __syncthreads();
        sc[tid] += t;
        __syncthreads();
    }
    if (tid < nbins) cur[tid] = sc[tid] - v;
    __syncthreads();
#pragma unroll
    for (int j = 0; j < PT; ++j) {
        if (pb[j] >= 0) {
            int pos = atomicAdd(&cur[pb[j]], 1);
            ebuf[pos] = pv[j];
        }
    }
    __syncthreads();
    for (int i = tid; i < cntE; i += NT) slab[beg + i] = ebuf[i];  // coalesced
    for (int i = tid; i < nbins; i += NT) {
        cnt[blockIdx.x * nbins + i] = hist[i];
        seg[blockIdx.x * nbins + i] = cur[i] - hist[i];
    }
}

// ---------- binsum: per-bin total over chunks ----------
__global__ __launch_bounds__(256) void binsum_kernel(const int* __restrict__ cnt,
                                                     int* __restrict__ btotal,
                                                     int nbins, int nblk) {
    __shared__ int r[256];
    const int bin = blockIdx.x, tid = threadIdx.x;
    int s = 0;
    for (int b = tid; b < nblk; b += 256) s += cnt[b * nbins + bin];
    r[tid] = s;
    __syncthreads();
    for (int off = 128; off; off >>= 1) {
        if (tid < off) r[tid] += r[tid + off];
        __syncthreads();
    }
    if (tid == 0) btotal[bin] = r[0];
}

// ---------- binscan: exclusive scan of bin totals ----------
__global__ __launch_bounds__(256) void binscan_kernel(const int* __restrict__ btotal,
                                                      int* __restrict__ binbase,
                                                      int* __restrict__ row_ptr,
                                                      int nbins, int n, int E) {
    __shared__ int s[256];
    const int tid = threadIdx.x;
    int v = (tid < nbins) ? btotal[tid] : 0;
    s[tid] = v;
    __syncthreads();
    for (int off = 1; off < 256; off <<= 1) {
        int t = (tid >= off) ? s[tid - off] : 0;
        __syncthreads();
        s[tid] += t;
        __syncthreads();
    }
    if (tid < nbins) binbase[tid] = s[tid] - v;
    if (tid == 0) row_ptr[n] = E;
}

// ---------- binB: per-bin merge — degree/dinv/row_ptr + contiguous esrc ----------
__global__ __launch_bounds__(256) void binB_kernel(const unsigned* __restrict__ slab,
                                                   const int* __restrict__ cnt,
                                                   const int* __restrict__ seg,
                                                   const int* __restrict__ binbase,
                                                   float* __restrict__ dinv,
                                                   int* __restrict__ row_ptr,
                                                   int* __restrict__ esrc,
                                                   int n, int nbins, int nblk) {
    constexpr int NT = 256;
    __shared__ int segc[MAXBLK], segs[MAXBLK];
    __shared__ int sc[NT];
    __shared__ int hist[256], lbase[256], cur[256];
    const int tid = threadIdx.x;
    const int bin = blockIdx.x;
    for (int b = tid; b < MAXBLK; b += NT) {
        segc[b] = (b < nblk) ? cnt[b * nbins + bin] : 0;
        segs[b] = (b < nblk) ? seg[b * nbins + bin] : 0;
    }
    hist[tid] = 0;
    __syncthreads();
    for (int b = tid; b < nblk; b += NT) {
        int c = segc[b];
        const unsigned* p = slab + (size_t)b * CHUNK + segs[b];
        for (int i = 0; i < c; ++i) atomicAdd(&hist[p[i] >> 16], 1);
    }
    __syncthreads();
    int v = hist[tid];
    sc[tid] = v;
    __syncthreads();
    for (int off = 1; off < NT; off <<= 1) {
        int t = (tid >= off) ? sc[tid - off] : 0;
        __syncthreads();
        sc[tid] += t;
        __syncthreads();
    }
    lbase[tid] = sc[tid] - v;
    cur[tid] = 0;
    const int base = binbase[bin];
    const int node = bin * 256 + tid;
    if (node < n) {
        dinv[node] = rsqrtf((float)v + 1.0f);  // +1 = self loop
        row_ptr[node] = base + lbase[tid];
    }
    __syncthreads();
    for (int b = tid; b < nblk; b += NT) {
        int c = segc[b];
        const unsigned* p = slab + (size_t)b * CHUNK + segs[b];
        for (int i = 0; i < c; ++i) {
            unsigned e = p[i];
            int local = e >> 16;
            int pos = base + lbase[local] + atomicAdd(&cur[local], 1);
            esrc[pos] = (int)(e & 0xFFFFu);
        }
    }
}

// ---------- GEMM: Hb[slice][row][32] = bf16( dinv[row] * (X @ W) ) ----------
// Slice-major write: uint4 octet c of row r -> table c/4, uint4 idx (c%4).
template <int F, int ROWS, int NT>
__global__ __launch_bounds__(NT) void gemm_tile(const float* __restrict__ X,
                                                const float* __restrict__ W,
                                                const float* __restrict__ dinv,
                                                uint4* __restrict__ Hb, int n) {
    constexpr int K = 96;
    constexpr int CQ2 = F / 8;
    __shared__ float sX[ROWS * K];
    __shared__ float sW[K * F];
    const int tid = threadIdx.x;
    const int row0 = blockIdx.x * ROWS;
    {
        const float4* Wv = (const float4*)W;
        float4* sWv = (float4*)sW;
        for (int i = tid; i < K * F / 4; i += NT) sWv[i] = Wv[i];
    }
    if (row0 + ROWS <= n) {
        const float4* Xv = (const float4*)(X + (size_t)row0 * K);
        float4* sXv = (float4*)sX;
        for (int i = tid; i < ROWS * K / 4; i += NT) sXv[i] = Xv[i];
    } else {
        for (int i = tid; i < ROWS * K; i += NT) {
            int r = row0 + i / K;
            sX[i] = (r < n) ? X[(size_t)r * K + (i % K)] : 0.0f;
        }
    }
    __syncthreads();
    const int rp = tid / CQ2;
    const int c = tid % CQ2;
    const int r0 = rp * 2;
    float4 a00 = {0, 0, 0, 0}, a01 = {0, 0, 0, 0};
    float4 a10 = {0, 0, 0, 0}, a11 = {0, 0, 0, 0};
    const float4* sWv = (const float4*)sW;
#pragma unroll 4
    for (int k = 0; k < K; ++k) {
        float x0 = sX[r0 * K + k];
        float x1 = sX[(r0 + 1) * K + k];
        float4 w0 = sWv[k * (F / 4) + c * 2];
        float4 w1 = sWv[k * (F / 4) + c * 2 + 1];
        a00.x += x0 * w0.x; a00.y += x0 * w0.y; a00.z += x0 * w0.z; a00.w += x0 * w0.w;
        a01.x += x0 * w1.x; a01.y += x0 * w1.y; a01.z += x0 * w1.z; a01.w += x0 * w1.w;
        a10.x += x1 * w0.x; a10.y += x1 * w0.y; a10.z += x1 * w0.z; a10.w += x1 * w0.w;
        a11.x += x1 * w1.x; a11.y += x1 * w1.y; a11.z += x1 * w1.z; a11.w += x1 * w1.w;
    }
    const int ra = row0 + r0, rb = ra + 1;
    const size_t tab = (size_t)(c >> 2) * n * 4 + (size_t)(c & 3);
    if (ra < n) {
        float d0 = dinv[ra];
        uint4 w;
        w.x = (unsigned)f2bf(a00.x * d0) | ((unsigned)f2bf(a00.y * d0) << 16);
        w.y = (unsigned)f2bf(a00.z * d0) | ((unsigned)f2bf(a00.w * d0) << 16);
        w.z = (unsigned)f2bf(a01.x * d0) | ((unsigned)f2bf(a01.y * d0) << 16);
        w.w = (unsigned)f2bf(a01.z * d0) | ((unsigned)f2bf(a01.w * d0) << 16);
        Hb[tab + (size_t)ra * 4] = w;
    }
    if (rb < n) {
        float d1 = dinv[rb];
        uint4 w;
        w.x = (unsigned)f2bf(a10.x * d1) | ((unsigned)f2bf(a10.y * d1) << 16);
        w.y = (unsigned)f2bf(a10.z * d1) | ((unsigned)f2bf(a10.w * d1) << 16);
        w.z = (unsigned)f2bf(a11.x * d1) | ((unsigned)f2bf(a11.y * d1) << 16);
        w.w = (unsigned)f2bf(a11.z * d1) | ((unsigned)f2bf(a11.w * d1) << 16);
        Hb[tab + (size_t)rb * 4] = w;
    }
}

// ---------- gather-aggregate + epilogue (slice-major bf16 table) ----------
// blockIdx.y = slice (32 features, [N][4] uint4, 3.2MB -> L2-resident).
// 4 threads per node, 8 features per thread.
#define ACC8(vv)                                                        \
    do {                                                                \
        acc0 += bflo(vv.x); acc1 += bfhi(vv.x);                         \
        acc2 += bflo(vv.y); acc3 += bfhi(vv.y);                         \
        acc4 += bflo(vv.z); acc5 += bfhi(vv.z);                         \
        acc6 += bflo(vv.w); acc7 += bfhi(vv.w);                         \
    } while (0)

template <int NPB, bool RELU, int NT, int OUTF>
__global__ __launch_bounds__(NT) void agg_kernel(const uint4* __restrict__ Hb,
                                                 const int* __restrict__ row_ptr,
                                                 const int* __restrict__ esrc,
                                                 const float* __restrict__ dinv,
                                                 const float* __restrict__ b,
                                                 float* __restrict__ out, int n) {
    const int slice = blockIdx.y;
    const uint4* __restrict__ H = Hb + (size_t)slice * n * 4;
    const int tid = threadIdx.x;
    const int node = blockIdx.x * NPB + (tid >> 2);
    const int q = tid & 3;
    if (node >= n) return;
    float acc0 = 0, acc1 = 0, acc2 = 0, acc3 = 0, acc4 = 0, acc5 = 0, acc6 = 0, acc7 = 0;
    {
        uint4 v = H[(size_t)node * 4 + q];  // self loop
        ACC8(v);
    }
    const int beg = row_ptr[node], end = row_ptr[node + 1];
    int e = beg;
    for (; e + 4 <= end; e += 4) {
        int s0 = esrc[e + 0], s1 = esrc[e + 1], s2 = esrc[e + 2], s3 = esrc[e + 3];
        uint4 v0 = H[(size_t)s0 * 4 + q];
        uint4 v1 = H[(size_t)s1 * 4 + q];
        uint4 v2 = H[(size_t)s2 * 4 + q];
        uint4 v3 = H[(size_t)s3 * 4 + q];
        ACC8(v0); ACC8(v1); ACC8(v2); ACC8(v3);
    }
    for (; e < end; ++e) {
        uint4 v = H[(size_t)esrc[e] * 4 + q];
        ACC8(v);
    }
    const float di = dinv[node];
    const int f0 = slice * 32 + q * 8;
    float4 o0, o1;
    o0.x = acc0 * di + b[f0 + 0];
    o0.y = acc1 * di + b[f0 + 1];
    o0.z = acc2 * di + b[f0 + 2];
    o0.w = acc3 * di + b[f0 + 3];
    o1.x = acc4 * di + b[f0 + 4];
    o1.y = acc5 * di + b[f0 + 5];
    o1.z = acc6 * di + b[f0 + 6];
    o1.w = acc7 * di + b[f0 + 7];
    if (RELU) {
        o0.x = fmaxf(o0.x, 0.0f); o0.y = fmaxf(o0.y, 0.0f);
        o0.z = fmaxf(o0.z, 0.0f); o0.w = fmaxf(o0.w, 0.0f);
        o1.x = fmaxf(o1.x, 0.0f); o1.y = fmaxf(o1.y, 0.0f);
        o1.z = fmaxf(o1.z, 0.0f); o1.w = fmaxf(o1.w, 0.0f);
    }
    float4* op = (float4*)(out + (size_t)node * OUTF + f0);
    op[0] = o0;
    op[1] = o1;
}

extern "C" void kernel_launch(void* const* d_in, const int* in_sizes, int n_in,
                              void* d_out, int out_size, void* d_ws, size_t ws_size,
                              hipStream_t stream) {
    const float* x   = (const float*)d_in[0];
    const int*  eidx = (const int*)d_in[1];
    const float* W1  = (const float*)d_in[2];
    const float* b1  = (const float*)d_in[3];
    const float* W2  = (const float*)d_in[4];
    const float* b2  = (const float*)d_in[5];

    const int IN = 96, HID = 96, OUT = 32;
    const int N = in_sizes[0] / IN;   // 50000 (<= 65536 for 16-bit packing)
    const int E = in_sizes[1] / 2;    // 800000
    const int* src = eidx;
    const int* dst = eidx + E;

    float* out  = (float*)d_out;
    float* x1   = out;                       // [N, 96] f32
    float* out2 = out + (size_t)N * HID;     // [N, 32] f32

    const int nbins = (N + 255) / 256;        // 196
    const int nblk = (E + CHUNK - 1) / CHUNK; // 391 (<= MAXBLK)

    auto align512 = [](size_t v) { return ((v + 511) / 512) * 512; };
    char* ws = (char*)d_ws;
    size_t off = 0;
    float* dinv     = (float*)(ws + off); off += align512((size_t)N * 4);
    int* row_ptr    = (int*)(ws + off);   off += align512((size_t)(N + 1) * 4);
    int* esrc       = (int*)(ws + off);   off += align512((size_t)E * 4);
    unsigned* slab  = (unsigned*)(ws + off); off += align512((size_t)E * 4);
    int* cnt        = (int*)(ws + off);   off += align512((size_t)nblk * nbins * 4);
    int* seg        = (int*)(ws + off);   off += align512((size_t)nblk * nbins * 4);
    int* btotal     = (int*)(ws + off);   off += align512(NBINS_CAP * 4);
    int* binbase    = (int*)(ws + off);   off += align512(NBINS_CAP * 4);
    uint4* hb       = (uint4*)(ws + off); off += align512((size_t)N * 96 * 2);

    // ---- CSR build (atomic-free, fully parallel) ----
    binA_kernel<256><<<nblk, 256, 0, stream>>>(src, dst, slab, cnt, seg, nbins, E);
    binsum_kernel<<<nbins, 256, 0, stream>>>(cnt, btotal, nbins, nblk);
    binscan_kernel<<<1, 256, 0, stream>>>(btotal, binbase, row_ptr, nbins, N, E);
    binB_kernel<<<nbins, 256, 0, stream>>>(slab, cnt, seg, binbase,
                                           dinv, row_ptr, esrc, N, nbins, nblk);

    // ---- Layer 1 ----
    gemm_tile<96, 32, 192><<<(N + 31) / 32, 192, 0, stream>>>(x, W1, dinv, hb, N);
    {
        dim3 grid((N + 63) / 64, 3);
        agg_kernel<64, true, 256, 96><<<grid, 256, 0, stream>>>(
            hb, row_ptr, esrc, dinv, b1, x1, N);
    }

    // ---- Layer 2 ----
    gemm_tile<32, 64, 128><<<(N + 63) / 64, 128, 0, stream>>>(x1, W2, dinv, hb, N);
    {
        dim3 grid((N + 63) / 64, 1);
        agg_kernel<64, false, 256, 32><<<grid, 256, 0, stream>>>(
            hb, row_ptr, esrc, dinv, b2, out2, N);
    }
}